// Round 4
// baseline (625.155 us; speedup 1.0000x reference)
//
#include <hip/hip_runtime.h>
#include <hip/hip_bf16.h>

#define S_LEN 2048
#define D_DIM 128
#define H_NUM 16

typedef float f32x4 __attribute__((ext_vector_type(4)));
typedef _Float16 f16x8 __attribute__((ext_vector_type(8)));
typedef _Float16 f16x4 __attribute__((ext_vector_type(4)));

__device__ __forceinline__ _Float16 f2h(float f) { return (_Float16)f; }

// ---- convert weights fp32 -> fp16 once per call (L2-resident afterwards) ----
__global__ __launch_bounds__(256) void wconv_kernel(
    const float* __restrict__ Wq, const float* __restrict__ Wk,
    const float* __restrict__ Wv, _Float16* __restrict__ Wb) {
    int i = blockIdx.x * 256 + threadIdx.x;   // 16384 total
    Wb[i]         = f2h(Wq[i]);
    Wb[16384 + i] = f2h(Wk[i]);
    Wb[32768 + i] = f2h(Wv[i]);
}

// ---- fused QKV projection: y = x @ W^T + b ; V written transposed ----
// grid: (BH=64) * (S/128=16) blocks, 256 threads (4 waves x 32 rows)
__global__ __launch_bounds__(256) void proj_kernel(
    const float* __restrict__ x,
    const float* __restrict__ bq, const float* __restrict__ bk,
    const float* __restrict__ bv,
    const _Float16* __restrict__ Wb,
    _Float16* __restrict__ Qg, _Float16* __restrict__ Kg, _Float16* __restrict__ Vt)
{
    const int blk = blockIdx.x;
    const int bh  = blk >> 4;
    const int st  = blk & 15;
    const int tid = threadIdx.x;
    const int w = tid >> 6, lane = tid & 63, g = lane >> 4, r16 = lane & 15;
    const int base = st * 128 + w * 32;

    // A fragments: x rows (f16), 2 row-sets x 4 k-steps
    f16x8 xf[2][4];
    #pragma unroll
    for (int rs = 0; rs < 2; ++rs) {
        const int row = base + rs * 16 + r16;
        const float* xr = x + (size_t)(bh * S_LEN + row) * D_DIM + g * 8;
        #pragma unroll
        for (int kk = 0; kk < 4; ++kk) {
            float4 a = *(const float4*)(xr + kk * 32);
            float4 b = *(const float4*)(xr + kk * 32 + 4);
            f16x8 f;
            f[0]=f2h(a.x); f[1]=f2h(a.y); f[2]=f2h(a.z); f[3]=f2h(a.w);
            f[4]=f2h(b.x); f[5]=f2h(b.y); f[6]=f2h(b.z); f[7]=f2h(b.w);
            xf[rs][kk] = f;
        }
    }

    #pragma unroll 1
    for (int p = 0; p < 3; ++p) {
        const float* bias = (p == 0) ? bq : (p == 1) ? bk : bv;
        const _Float16* W = Wb + p * 16384;
        f32x4 acc[2][8];
        #pragma unroll
        for (int rs = 0; rs < 2; ++rs)
            #pragma unroll
            for (int et = 0; et < 8; ++et)
                acc[rs][et] = (f32x4){0.f, 0.f, 0.f, 0.f};

        #pragma unroll
        for (int et = 0; et < 8; ++et) {
            const _Float16* wr = W + (size_t)(et * 16 + r16) * 128 + g * 8;
            #pragma unroll
            for (int kk = 0; kk < 4; ++kk) {
                f16x8 wf = *(const f16x8*)(wr + kk * 32);
                acc[0][et] = __builtin_amdgcn_mfma_f32_16x16x32_f16(xf[0][kk], wf, acc[0][et], 0, 0, 0);
                acc[1][et] = __builtin_amdgcn_mfma_f32_16x16x32_f16(xf[1][kk], wf, acc[1][et], 0, 0, 0);
            }
        }

        // epilogue: C layout col = lane&15, row = (lane>>4)*4 + i
        #pragma unroll
        for (int et = 0; et < 8; ++et) {
            const float be = bias[et * 16 + r16];
            #pragma unroll
            for (int rs = 0; rs < 2; ++rs) {
                const int row0 = base + rs * 16 + g * 4;
                if (p == 2) {
                    f16x4 vv;
                    vv[0] = f2h(acc[rs][et][0] + be);
                    vv[1] = f2h(acc[rs][et][1] + be);
                    vv[2] = f2h(acc[rs][et][2] + be);
                    vv[3] = f2h(acc[rs][et][3] + be);
                    *(f16x4*)(Vt + (size_t)bh * D_DIM * S_LEN
                                 + (size_t)(et * 16 + r16) * S_LEN + row0) = vv;
                } else {
                    _Float16* O = (p == 0) ? Qg : Kg;
                    #pragma unroll
                    for (int i = 0; i < 4; ++i)
                        O[(size_t)(bh * S_LEN + row0 + i) * D_DIM + et * 16 + r16]
                            = f2h(acc[rs][et][i] + be);
                }
            }
        }
    }
}

// ---- flash attention: 64 q-rows/block (4 waves x 16), KV tile = 64 ----
// grid: BH*32 = 2048 blocks, 256 threads
__global__ __launch_bounds__(256) void attn_kernel(
    const _Float16* __restrict__ Qg, const _Float16* __restrict__ Kg,
    const _Float16* __restrict__ Vt, float* __restrict__ out)
{
    __shared__ _Float16 k_lds[64][144];     // +16 pad: 4-way conflict max
    __shared__ _Float16 v_lds[128][80];     // V^T tile, +16 pad
    __shared__ _Float16 p_lds[4][16][80];   // per-wave P reshape buffer

    const int blk = blockIdx.x;
    const int bh = blk >> 5;
    const int qt = blk & 31;
    const int b = bh >> 4, h = bh & 15;
    const int tid = threadIdx.x;
    const int w = tid >> 6, lane = tid & 63, g = lane >> 4, r16 = lane & 15;

    // Q fragments (held in registers for the whole KV loop)
    f16x8 qf[4];
    {
        const int qrow = qt * 64 + w * 16 + r16;
        const _Float16* qp = Qg + (size_t)(bh * S_LEN + qrow) * D_DIM + g * 8;
        #pragma unroll
        for (int kk = 0; kk < 4; ++kk) qf[kk] = *(const f16x8*)(qp + kk * 32);
    }

    f32x4 acc[8];
    #pragma unroll
    for (int dt = 0; dt < 8; ++dt) acc[dt] = (f32x4){0.f, 0.f, 0.f, 0.f};
    float m[4], l[4];
    #pragma unroll
    for (int i = 0; i < 4; ++i) { m[i] = -1e30f; l[i] = 0.f; }

    const _Float16* Kb = Kg + (size_t)bh * S_LEN * D_DIM;
    const _Float16* Vb = Vt + (size_t)bh * D_DIM * S_LEN;
    const float LOG2E = 1.4426950408889634f;

    for (int kv = 0; kv < 32; ++kv) {
        // stage K tile [64][128] and V^T tile [128][64] -> LDS
        #pragma unroll
        for (int cc = 0; cc < 4; ++cc) {
            const int off = (tid + cc * 256) * 8;
            const int r = off >> 7, c = off & 127;
            *(uint4*)&k_lds[r][c] =
                *(const uint4*)(Kb + (size_t)(kv * 64 + r) * D_DIM + c);
            const int d = off >> 6, c2 = off & 63;
            *(uint4*)&v_lds[d][c2] =
                *(const uint4*)(Vb + (size_t)d * S_LEN + kv * 64 + c2);
        }
        __syncthreads();

        // S = Q K^T  (16 q-rows x 64 keys per wave)
        f32x4 sacc[4];
        #pragma unroll
        for (int ct = 0; ct < 4; ++ct) sacc[ct] = (f32x4){0.f, 0.f, 0.f, 0.f};
        #pragma unroll
        for (int kk = 0; kk < 4; ++kk) {
            f16x8 qk = qf[kk];
            #pragma unroll
            for (int ct = 0; ct < 4; ++ct) {
                f16x8 kf = *(const f16x8*)&k_lds[ct * 16 + r16][kk * 32 + g * 8];
                sacc[ct] = __builtin_amdgcn_mfma_f32_16x16x32_f16(qk, kf, sacc[ct], 0, 0, 0);
            }
        }

        // online softmax (rows g*4+i live in the 16 lanes of quarter g)
        float alpha[4], rsum[4];
        #pragma unroll
        for (int i = 0; i < 4; ++i) {
            float t = fmaxf(fmaxf(sacc[0][i], sacc[1][i]),
                            fmaxf(sacc[2][i], sacc[3][i]));
            t = fmaxf(t, __shfl_xor(t, 1, 64));
            t = fmaxf(t, __shfl_xor(t, 2, 64));
            t = fmaxf(t, __shfl_xor(t, 4, 64));
            t = fmaxf(t, __shfl_xor(t, 8, 64));
            const float nm = fmaxf(m[i], t);
            alpha[i] = exp2f((m[i] - nm) * LOG2E);
            m[i] = nm;
            rsum[i] = 0.f;
        }
        #pragma unroll
        for (int ct = 0; ct < 4; ++ct) {
            #pragma unroll
            for (int i = 0; i < 4; ++i) {
                const float pv = exp2f((sacc[ct][i] - m[i]) * LOG2E);
                rsum[i] += pv;
                p_lds[w][g * 4 + i][ct * 16 + r16] = f2h(pv);
            }
        }
        #pragma unroll
        for (int i = 0; i < 4; ++i) {
            float t = rsum[i];
            t += __shfl_xor(t, 1, 64);
            t += __shfl_xor(t, 2, 64);
            t += __shfl_xor(t, 4, 64);
            t += __shfl_xor(t, 8, 64);
            l[i] = l[i] * alpha[i] + t;
        }
        #pragma unroll
        for (int dt = 0; dt < 8; ++dt)
            #pragma unroll
            for (int i = 0; i < 4; ++i)
                acc[dt][i] *= alpha[i];

        // O += P V  (P from per-wave LDS reshape; V^T gives contiguous keys)
        f16x8 pf[2];
        #pragma unroll
        for (int ks = 0; ks < 2; ++ks)
            pf[ks] = *(const f16x8*)&p_lds[w][r16][ks * 32 + g * 8];
        #pragma unroll
        for (int ks = 0; ks < 2; ++ks) {
            #pragma unroll
            for (int dt = 0; dt < 8; ++dt) {
                f16x8 vf = *(const f16x8*)&v_lds[dt * 16 + r16][ks * 32 + g * 8];
                acc[dt] = __builtin_amdgcn_mfma_f32_16x16x32_f16(pf[ks], vf, acc[dt], 0, 0, 0);
            }
        }
        __syncthreads();
    }

    // epilogue: out[b][s*H + h][d] = acc/l
    #pragma unroll
    for (int dt = 0; dt < 8; ++dt) {
        #pragma unroll
        for (int i = 0; i < 4; ++i) {
            const int s = qt * 64 + w * 16 + g * 4 + i;
            out[(((size_t)b * S_LEN + s) * H_NUM + h) * D_DIM + dt * 16 + r16]
                = acc[dt][i] / l[i];
        }
    }
}

extern "C" void kernel_launch(void* const* d_in, const int* in_sizes, int n_in,
                              void* d_out, int out_size, void* d_ws, size_t ws_size,
                              hipStream_t stream) {
    const float* x  = (const float*)d_in[0];
    const float* Wq = (const float*)d_in[1];
    const float* bq = (const float*)d_in[2];
    const float* Wk = (const float*)d_in[3];
    const float* bk = (const float*)d_in[4];
    const float* Wv = (const float*)d_in[5];
    const float* bv = (const float*)d_in[6];
    float* out = (float*)d_out;

    char* ws = (char*)d_ws;
    _Float16* Wb  = (_Float16*)ws;                     // 3*16384 f16 = 96 KB
    _Float16* Qg  = (_Float16*)(ws + 131072);          // 64*2048*128 f16 = 32 MB
    _Float16* Kg  = Qg + (size_t)64 * S_LEN * D_DIM;
    _Float16* Vtg = Kg + (size_t)64 * S_LEN * D_DIM;   // transposed V

    wconv_kernel<<<64, 256, 0, stream>>>(Wq, Wk, Wv, Wb);
    proj_kernel<<<1024, 256, 0, stream>>>(x, bq, bk, bv, Wb, Qg, Kg, Vtg);
    attn_kernel<<<2048, 256, 0, stream>>>(Qg, Kg, Vtg, out);
}